// Round 5
// baseline (121.268 us; speedup 1.0000x reference)
//
#include <hip/hip_runtime.h>
#include <hip/hip_bf16.h>
#include <math.h>

// Problem: B_SZ=2, L=2048, D=1024, N=16.  M = B_SZ*L = 4096.
// y[m,d] = x[m,d] * softplus((x@W1^T)[m,d] + b1[d]) * s[m]
// s[m]   = sum_n (x_m . W2_n + b2_n) * (x_m . W3_n + b3_n)
// A is unused (multiplies a zero-initialized h in the reference).

typedef __bf16 bf16x8 __attribute__((ext_vector_type(8)));
typedef __bf16 bf16x4 __attribute__((ext_vector_type(4)));
typedef float  f32x4  __attribute__((ext_vector_type(4)));

#define MDIM 4096
#define KDIM 1024
#define NDIM 1024

// async global->LDS, 16B per lane; LDS dest = wave-uniform base + lane*16.
__device__ __forceinline__ void async16(const void* g, void* l) {
    __builtin_amdgcn_global_load_lds(
        (const __attribute__((address_space(1))) void*)g,
        (__attribute__((address_space(3))) void*)l, 16, 0, 0);
}

__device__ __forceinline__ float softplus_f(float z) {
    return fmaxf(z, 0.f) + log1pf(__expf(-fabsf(z)));
}

__device__ __forceinline__ float dot4(float4 a, float4 b) {
    return a.x * b.x + a.y * b.y + a.z * b.z + a.w * b.w;
}

// ============ convert_s: x,W1 -> bf16  AND  s, lean version ============
// 1024 blocks x 256 thr. Block b: x rows 4b..4b+3 (wave w converts row w).
// Dots: wave w handles Wc rows [w*8, w*8+8) of [W2;W3], lane l covers
// k-slice {l*4+s*256}: W row reads are contiguous 1KB per wave per step.
__global__ __launch_bounds__(256)
void convert_s(const float* __restrict__ x, const float* __restrict__ W1,
               const float* __restrict__ W2, const float* __restrict__ b2,
               const float* __restrict__ W3, const float* __restrict__ b3,
               __bf16* __restrict__ xb, __bf16* __restrict__ w1b,
               float* __restrict__ s) {
    __shared__ float xs[4][1024];   // 16 KB
    __shared__ float part[32][4];
    const int t = threadIdx.x;
    const int wave = t >> 6, lane = t & 63;
    const size_t m0 = (size_t)blockIdx.x * 4;

    // ---- W1 grid-share convert: 256 float4 per block ----
    {
        const size_t i = (size_t)blockIdx.x * 256 + t;
        float4 v = reinterpret_cast<const float4*>(W1)[i];
        bf16x4 h = { (__bf16)v.x, (__bf16)v.y, (__bf16)v.z, (__bf16)v.w };
        reinterpret_cast<bf16x4*>(w1b)[i] = h;
    }

    // ---- x row `wave`: fp32 -> bf16 global + fp32 LDS (coalesced) ----
    {
        const float4* src = reinterpret_cast<const float4*>(x + (m0 + wave) * KDIM);
        bf16x4* dst = reinterpret_cast<bf16x4*>(xb + (m0 + wave) * KDIM);
#pragma unroll
        for (int s4 = 0; s4 < 4; ++s4) {
            float4 v = src[lane + s4 * 64];
            bf16x4 h = { (__bf16)v.x, (__bf16)v.y, (__bf16)v.z, (__bf16)v.w };
            dst[lane + s4 * 64] = h;
            *reinterpret_cast<float4*>(&xs[wave][(lane + s4 * 64) * 4]) = v;
        }
    }
    __syncthreads();

    // ---- gather this lane's x slice for all 4 rows (conflict-free b128) ----
    float4 X[4][4];
#pragma unroll
    for (int r = 0; r < 4; ++r)
#pragma unroll
        for (int s4 = 0; s4 < 4; ++s4)
            X[r][s4] = *reinterpret_cast<const float4*>(&xs[r][(lane + s4 * 64) * 4]);

    // ---- dots: wave's 8 Wc rows; coalesced W reads; butterfly reduce ----
#pragma unroll
    for (int wr = 0; wr < 8; ++wr) {
        const int gr = wave * 8 + wr;   // 0..31 (wave-uniform)
        const float* __restrict__ Wrow = (gr < 16)
            ? (W2 + (size_t)gr * KDIM) : (W3 + (size_t)(gr - 16) * KDIM);
        float4 Wv[4];
#pragma unroll
        for (int s4 = 0; s4 < 4; ++s4)
            Wv[s4] = reinterpret_cast<const float4*>(Wrow)[lane + s4 * 64];
        float p[4];
#pragma unroll
        for (int r = 0; r < 4; ++r) {
            float a = dot4(Wv[0], X[r][0]) + dot4(Wv[1], X[r][1])
                    + dot4(Wv[2], X[r][2]) + dot4(Wv[3], X[r][3]);
#pragma unroll
            for (int d = 1; d < 64; d <<= 1) a += __shfl_xor(a, d);
            p[r] = a;
        }
        if (lane == 0) {
            part[gr][0] = p[0]; part[gr][1] = p[1];
            part[gr][2] = p[2]; part[gr][3] = p[3];
        }
    }
    __syncthreads();

    // ---- s: 64 threads, (r = t>>4, n = t&15) ----
    if (t < 64) {
        const int r = t >> 4, n = t & 15;
        float v = (part[n][r] + b2[n]) * (part[n + 16][r] + b3[n]);
        v += __shfl_xor(v, 1);
        v += __shfl_xor(v, 2);
        v += __shfl_xor(v, 4);
        v += __shfl_xor(v, 8);
        if (n == 0) s[m0 + r] = v;
    }
}

// ============ main GEMM: y = x * softplus(xb@w1b^T + b1) * s ============
// 128x64x64 tiles, 512 blocks. Double-buffered LDS, ONE barrier per k-iter:
// barrier -> prefetch buf[p^1] (flies during compute) -> ds_read/MFMA buf[p].
#define GBM 128
#define GBN 64
#define GBK 64
#define NIT (KDIM / GBK)
__global__ __launch_bounds__(256)
void gemm_bf(const __bf16* __restrict__ xb, const __bf16* __restrict__ w1b,
             const float* __restrict__ x, const float* __restrict__ b1,
             const float* __restrict__ s, float* __restrict__ y) {
    __shared__ __align__(16) __bf16 As[2][GBM * GBK];  // 32 KB
    __shared__ __align__(16) __bf16 Bs[2][GBN * GBK];  // 16 KB
    const int bm = blockIdx.y, bn = blockIdx.x;
    const int t = threadIdx.x;
    const int wave = t >> 6, lane = t & 63;
    const int wm = (wave >> 1) * 64, wn = (wave & 1) * 32;
    const int lrow = lane & 15, quad = lane >> 4;
    const int srow = lane >> 3;                 // row within 8-row chunk
    const int scol = ((lane & 7) ^ srow) * 8;   // XOR-swizzled source col group
    const size_t m0 = (size_t)bm * GBM, n0 = (size_t)bn * GBN;

    f32x4 acc[4][2] = {};

    // prologue: fill buffer 0
#pragma unroll
    for (int i = 0; i < 4; ++i) {
        int q = i * 4 + wave; int row = 8 * q + srow;
        async16(xb + (m0 + row) * KDIM + scol, &As[0][q * 512]);
    }
#pragma unroll
    for (int i = 0; i < 2; ++i) {
        int q = i * 4 + wave; int row = 8 * q + srow;
        async16(w1b + (n0 + row) * KDIM + scol, &Bs[0][q * 512]);
    }

    for (int it = 0; it < NIT; ++it) {
        const int p = it & 1;
        __syncthreads();   // drains buf[p] fill; protects buf[p^1] reuse

        if (it + 1 < NIT) {
            const int k1 = (it + 1) * GBK;
#pragma unroll
            for (int i = 0; i < 4; ++i) {
                int q = i * 4 + wave; int row = 8 * q + srow;
                async16(xb + (m0 + row) * KDIM + k1 + scol, &As[p ^ 1][q * 512]);
            }
#pragma unroll
            for (int i = 0; i < 2; ++i) {
                int q = i * 4 + wave; int row = 8 * q + srow;
                async16(w1b + (n0 + row) * KDIM + k1 + scol, &Bs[p ^ 1][q * 512]);
            }
        }

#pragma unroll
        for (int kk = 0; kk < GBK; kk += 32) {
            const int cg = (kk >> 3) + quad;  // logical col group 0..7
            bf16x8 af[4], bfr[2];
#pragma unroll
            for (int mi = 0; mi < 4; ++mi) {
                int row = wm + mi * 16 + lrow;
                af[mi] = *reinterpret_cast<const bf16x8*>(
                    &As[p][row * GBK + ((cg ^ (row & 7)) << 3)]);
            }
#pragma unroll
            for (int ni = 0; ni < 2; ++ni) {
                int row = wn + ni * 16 + lrow;
                bfr[ni] = *reinterpret_cast<const bf16x8*>(
                    &Bs[p][row * GBK + ((cg ^ (row & 7)) << 3)]);
            }
#pragma unroll
            for (int mi = 0; mi < 4; ++mi)
#pragma unroll
                for (int ni = 0; ni < 2; ++ni)
                    acc[mi][ni] = __builtin_amdgcn_mfma_f32_16x16x32_bf16(
                        af[mi], bfr[ni], acc[mi][ni], 0, 0, 0);
        }
    }

    // ---- epilogue: y = x * softplus(acc + b1) * s ----
#pragma unroll
    for (int ni = 0; ni < 2; ++ni) {
        const size_t gn = n0 + wn + ni * 16 + lrow;
        const float bias = b1[gn];
#pragma unroll
        for (int mi = 0; mi < 4; ++mi) {
#pragma unroll
            for (int r = 0; r < 4; ++r) {
                const size_t gm = m0 + wm + mi * 16 + quad * 4 + r;
                float z = acc[mi][ni][r] + bias;
                y[gm * NDIM + gn] = x[gm * NDIM + gn] * softplus_f(z) * s[gm];
            }
        }
    }
}

// ================= fallback path (ws too small): round-0 kernels =============
__global__ __launch_bounds__(256)
void s_kernel_fb(const float* __restrict__ x,
                 const float* __restrict__ W2, const float* __restrict__ b2,
                 const float* __restrict__ W3, const float* __restrict__ b3,
                 float* __restrict__ s) {
    __shared__ float xs[1024];
    __shared__ float ps[8][32];
    __shared__ float bc[32];
    const int m = blockIdx.x;
    const int t = threadIdx.x;
    reinterpret_cast<float4*>(xs)[t] =
        reinterpret_cast<const float4*>(x + (size_t)m * 1024)[t];
    __syncthreads();
    const int n = t & 15;
    const int mat = (t >> 4) & 1;
    const int seg = t >> 5;
    const float* __restrict__ W = mat ? W3 : W2;
    const float* __restrict__ wr = W + (size_t)n * 1024 + seg * 128;
    const float* __restrict__ xr = xs + seg * 128;
    float p = 0.f;
#pragma unroll
    for (int i = 0; i < 128; i += 4) {
        float4 w4 = *reinterpret_cast<const float4*>(wr + i);
        float4 x4 = *reinterpret_cast<const float4*>(xr + i);
        p += w4.x * x4.x + w4.y * x4.y + w4.z * x4.z + w4.w * x4.w;
    }
    ps[seg][t & 31] = p;
    __syncthreads();
    if (t < 32) {
        float tot = 0.f;
#pragma unroll
        for (int g = 0; g < 8; ++g) tot += ps[g][t];
        tot += (t < 16) ? b2[t] : b3[t - 16];
        bc[t] = tot;
    }
    __syncthreads();
    if (t == 0) {
        float ss = 0.f;
#pragma unroll
        for (int nn = 0; nn < 16; ++nn) ss += bc[nn] * bc[16 + nn];
        s[m] = ss;
    }
}

#define BM 128
#define BN 64
#define BK 64
#define LDK 72
__global__ __launch_bounds__(256)
void gemm_fused_fb(const float* __restrict__ x, const float* __restrict__ W1,
                   const float* __restrict__ b1, const float* __restrict__ s,
                   float* __restrict__ y) {
    __shared__ __align__(16) __bf16 As[BM * LDK];
    __shared__ __align__(16) __bf16 Bs[BN * LDK];
    const int bm = blockIdx.y;
    const int bn = blockIdx.x;
    const int t = threadIdx.x;
    const int wave = t >> 6;
    const int lane = t & 63;
    const int wm = (wave >> 1) * 64;
    const int wn = (wave & 1) * 32;
    const int lrow = lane & 15;
    const int quad = lane >> 4;
    f32x4 acc[4][2] = {};
    const int rbase = t >> 4;
    const int scol = (t & 15) * 4;
    const float* __restrict__ xg = x + (size_t)(bm * BM) * KDIM + scol;
    const float* __restrict__ wg = W1 + (size_t)(bn * BN) * KDIM + scol;
    for (int k0 = 0; k0 < KDIM; k0 += BK) {
#pragma unroll
        for (int rr = 0; rr < 8; ++rr) {
            int row = rr * 16 + rbase;
            float4 v = *reinterpret_cast<const float4*>(xg + (size_t)row * KDIM + k0);
            bf16x4 h = { (__bf16)v.x, (__bf16)v.y, (__bf16)v.z, (__bf16)v.w };
            *reinterpret_cast<bf16x4*>(&As[row * LDK + scol]) = h;
        }
#pragma unroll
        for (int rr = 0; rr < 4; ++rr) {
            int row = rr * 16 + rbase;
            float4 v = *reinterpret_cast<const float4*>(wg + (size_t)row * KDIM + k0);
            bf16x4 h = { (__bf16)v.x, (__bf16)v.y, (__bf16)v.z, (__bf16)v.w };
            *reinterpret_cast<bf16x4*>(&Bs[row * LDK + scol]) = h;
        }
        __syncthreads();
#pragma unroll
        for (int kk = 0; kk < BK; kk += 32) {
            bf16x8 af[4];
            bf16x8 bfr[2];
#pragma unroll
            for (int mi = 0; mi < 4; ++mi)
                af[mi] = *reinterpret_cast<const bf16x8*>(
                    &As[(wm + mi * 16 + lrow) * LDK + kk + quad * 8]);
#pragma unroll
            for (int ni = 0; ni < 2; ++ni)
                bfr[ni] = *reinterpret_cast<const bf16x8*>(
                    &Bs[(wn + ni * 16 + lrow) * LDK + kk + quad * 8]);
#pragma unroll
            for (int mi = 0; mi < 4; ++mi)
#pragma unroll
                for (int ni = 0; ni < 2; ++ni)
                    acc[mi][ni] = __builtin_amdgcn_mfma_f32_16x16x32_bf16(
                        af[mi], bfr[ni], acc[mi][ni], 0, 0, 0);
        }
        __syncthreads();
    }
    const int gmb = bm * BM + wm;
    const int gnb = bn * BN + wn;
#pragma unroll
    for (int ni = 0; ni < 2; ++ni) {
        const int gn = gnb + ni * 16 + lrow;
        const float bias = b1[gn];
#pragma unroll
        for (int mi = 0; mi < 4; ++mi) {
            const int gm0 = gmb + mi * 16 + quad * 4;
#pragma unroll
            for (int r = 0; r < 4; ++r) {
                const int gm = gm0 + r;
                float z = acc[mi][ni][r] + bias;
                y[(size_t)gm * NDIM + gn] =
                    x[(size_t)gm * NDIM + gn] * softplus_f(z) * s[gm];
            }
        }
    }
}

extern "C" void kernel_launch(void* const* d_in, const int* in_sizes, int n_in,
                              void* d_out, int out_size, void* d_ws, size_t ws_size,
                              hipStream_t stream) {
    const float* x  = (const float*)d_in[0];
    const float* W1 = (const float*)d_in[1];
    const float* b1 = (const float*)d_in[2];
    const float* W2 = (const float*)d_in[3];
    const float* b2 = (const float*)d_in[4];
    const float* W3 = (const float*)d_in[5];
    const float* b3 = (const float*)d_in[6];
    // d_in[7] = A : unused

    float* y = (float*)d_out;

    const size_t XB_BYTES = (size_t)MDIM * KDIM * 2;   // 8 MB
    const size_t WB_BYTES = (size_t)NDIM * KDIM * 2;   // 2 MB
    const size_t S_BYTES  = (size_t)MDIM * 4;          // 16 KB

    if (ws_size >= XB_BYTES + WB_BYTES + S_BYTES) {
        __bf16* xb  = (__bf16*)d_ws;
        __bf16* w1b = (__bf16*)((char*)d_ws + XB_BYTES);
        float*  s   = (float*)((char*)d_ws + XB_BYTES + WB_BYTES);
        convert_s<<<dim3(MDIM / 4), dim3(256), 0, stream>>>(
            x, W1, W2, b2, W3, b3, xb, w1b, s);
        gemm_bf<<<dim3(NDIM / GBN, MDIM / GBM), dim3(256), 0, stream>>>(
            xb, w1b, x, b1, s, y);
    } else {
        float* s = (float*)d_ws;
        s_kernel_fb<<<dim3(MDIM), dim3(256), 0, stream>>>(x, W2, b2, W3, b3, s);
        gemm_fused_fb<<<dim3(NDIM / BN, MDIM / BM), dim3(256), 0, stream>>>(x, W1, b1, s, y);
    }
}